// Round 3
// baseline (53.172 us; speedup 1.0000x reference)
//
#include <hip/hip_runtime.h>

// SVMProjection: out[n,d] = x[n,d] - ((x[n,:]-bias)·cav) * cav[d]
//   (uses (x·cav - bias·cav) == (x-bias)·cav to fuse the bias projection
//    into each block's reduction — no separate serial 1-block kernel)
// N=8192 rows, D=4096 cols, fp32. Memory-bound: read x once + write out once.

#define DIM 4096
#define NTHREADS 256
#define V4_PER_ROW (DIM / 4)                    // 1024 float4 per row
#define V4_PER_THREAD (V4_PER_ROW / NTHREADS)   // 4

// native clang vector type — accepted by __builtin_nontemporal_{load,store}
typedef float f32x4 __attribute__((ext_vector_type(4)));

__global__ void __launch_bounds__(NTHREADS)
svm_proj_kernel(const float* __restrict__ x, const float* __restrict__ cav,
                const float* __restrict__ bias, float* __restrict__ out) {
    const int row = blockIdx.x;
    const int t = threadIdx.x;

    const f32x4* xr = reinterpret_cast<const f32x4*>(x + (size_t)row * DIM);
    const f32x4* c4 = reinterpret_cast<const f32x4*>(cav);
    const f32x4* b4 = reinterpret_cast<const f32x4*>(bias);

    f32x4 xv[V4_PER_THREAD];
    f32x4 cv[V4_PER_THREAD];
    float s = 0.0f;
    #pragma unroll
    for (int k = 0; k < V4_PER_THREAD; ++k) {
        const int i = t + k * NTHREADS;          // lane-contiguous float4: 1 KiB/wave/instr
        xv[k] = __builtin_nontemporal_load(&xr[i]);  // x is touch-once: bypass L2 pollution
        cv[k] = c4[i];                            // cav: L2-resident, normal load
        const f32x4 b = b4[i];                    // bias: L2-resident
        s += (xv[k].x - b.x) * cv[k].x + (xv[k].y - b.y) * cv[k].y
           + (xv[k].z - b.z) * cv[k].z + (xv[k].w - b.w) * cv[k].w;
    }

    // wave64 shfl reduce, then cross-wave via LDS
    #pragma unroll
    for (int off = 32; off > 0; off >>= 1) s += __shfl_down(s, off, 64);

    __shared__ float ls[NTHREADS / 64];
    const int wave = t >> 6;
    if ((t & 63) == 0) ls[wave] = s;
    __syncthreads();

    float sc = 0.0f;                              // sc = (x-bias)·cav
    #pragma unroll
    for (int w = 0; w < NTHREADS / 64; ++w) sc += ls[w];

    f32x4* orow = reinterpret_cast<f32x4*>(out + (size_t)row * DIM);
    #pragma unroll
    for (int k = 0; k < V4_PER_THREAD; ++k) {
        const int i = t + k * NTHREADS;
        f32x4 o;
        o.x = xv[k].x - sc * cv[k].x;
        o.y = xv[k].y - sc * cv[k].y;
        o.z = xv[k].z - sc * cv[k].z;
        o.w = xv[k].w - sc * cv[k].w;
        __builtin_nontemporal_store(o, &orow[i]); // out is write-once: don't cache
    }
}

extern "C" void kernel_launch(void* const* d_in, const int* in_sizes, int n_in,
                              void* d_out, int out_size, void* d_ws, size_t ws_size,
                              hipStream_t stream) {
    const float* x    = reinterpret_cast<const float*>(d_in[0]);
    const float* cav  = reinterpret_cast<const float*>(d_in[1]);
    const float* bias = reinterpret_cast<const float*>(d_in[2]);
    float* out = reinterpret_cast<float*>(d_out);

    const int N = in_sizes[0] / DIM;   // 8192

    svm_proj_kernel<<<N, NTHREADS, 0, stream>>>(x, cav, bias, out);
}

// Round 4
// 43.230 us; speedup vs baseline: 1.2300x; 1.2300x over previous
//
#include <hip/hip_runtime.h>

// SVMProjection: out[n,d] = x[n,d] - ((x[n,:]-bias)·cav) * cav[d]
//   (uses (x·cav - bias·cav) == (x-bias)·cav to fuse the bias projection
//    into each block's reduction — no separate serial 1-block kernel)
// N=8192 rows, D=4096 cols, fp32. Memory-bound: read x once + write out once.
// R3 lesson: nontemporal hints regressed (53.2 vs 48.4 µs) — removed.

#define DIM 4096
#define NTHREADS 256
#define V4_PER_ROW (DIM / 4)                    // 1024 float4 per row
#define V4_PER_THREAD (V4_PER_ROW / NTHREADS)   // 4

__global__ void __launch_bounds__(NTHREADS)
svm_proj_kernel(const float* __restrict__ x, const float* __restrict__ cav,
                const float* __restrict__ bias, float* __restrict__ out) {
    const int row = blockIdx.x;
    const int t = threadIdx.x;

    const float4* xr = reinterpret_cast<const float4*>(x + (size_t)row * DIM);
    const float4* c4 = reinterpret_cast<const float4*>(cav);
    const float4* b4 = reinterpret_cast<const float4*>(bias);

    float4 xv[V4_PER_THREAD];
    float4 cv[V4_PER_THREAD];
    float s = 0.0f;
    #pragma unroll
    for (int k = 0; k < V4_PER_THREAD; ++k) {
        const int i = t + k * NTHREADS;          // lane-contiguous float4: 1 KiB/wave/instr
        xv[k] = xr[i];
        cv[k] = c4[i];                            // cav: L1/L2-resident
        const float4 b = b4[i];                   // bias: L1/L2-resident
        s += (xv[k].x - b.x) * cv[k].x + (xv[k].y - b.y) * cv[k].y
           + (xv[k].z - b.z) * cv[k].z + (xv[k].w - b.w) * cv[k].w;
    }

    // wave64 shfl reduce, then cross-wave via LDS
    #pragma unroll
    for (int off = 32; off > 0; off >>= 1) s += __shfl_down(s, off, 64);

    __shared__ float ls[NTHREADS / 64];
    const int wave = t >> 6;
    if ((t & 63) == 0) ls[wave] = s;
    __syncthreads();

    float sc = 0.0f;                              // sc = (x-bias)·cav
    #pragma unroll
    for (int w = 0; w < NTHREADS / 64; ++w) sc += ls[w];

    float4* orow = reinterpret_cast<float4*>(out + (size_t)row * DIM);
    #pragma unroll
    for (int k = 0; k < V4_PER_THREAD; ++k) {
        const int i = t + k * NTHREADS;
        float4 o;
        o.x = xv[k].x - sc * cv[k].x;
        o.y = xv[k].y - sc * cv[k].y;
        o.z = xv[k].z - sc * cv[k].z;
        o.w = xv[k].w - sc * cv[k].w;
        orow[i] = o;
    }
}

extern "C" void kernel_launch(void* const* d_in, const int* in_sizes, int n_in,
                              void* d_out, int out_size, void* d_ws, size_t ws_size,
                              hipStream_t stream) {
    const float* x    = reinterpret_cast<const float*>(d_in[0]);
    const float* cav  = reinterpret_cast<const float*>(d_in[1]);
    const float* bias = reinterpret_cast<const float*>(d_in[2]);
    float* out = reinterpret_cast<float*>(d_out);

    const int N = in_sizes[0] / DIM;   // 8192

    svm_proj_kernel<<<N, NTHREADS, 0, stream>>>(x, cav, bias, out);
}